// Round 16
// baseline (400.051 us; speedup 1.0000x reference)
//
#include <hip/hip_runtime.h>
#include <hip/hip_bf16.h>
#include <math.h>

#define N_NODESC 32768
#define N_EDGESC 524288
#define NPG 8192
#define KOUT 512

typedef unsigned short u16;
typedef unsigned int u32;
typedef unsigned long long u64;

__device__ __forceinline__ float siluf(float x) {
    return x / (1.f + __expf(-x));
}

// ---------------- h0 = x@proj_w + proj_b + sincos(mesh_pos)  (+ zero deg) ----------------
__global__ __launch_bounds__(256) void k_h0(const float* __restrict__ x,
                                            const float* __restrict__ pos,
                                            const float* __restrict__ pw,
                                            const float* __restrict__ pb,
                                            float* __restrict__ h,
                                            int* __restrict__ deg) {
    int gid = blockIdx.x * 256 + threadIdx.x;
    if (gid < N_NODESC) deg[gid] = 0;
    int node = blockIdx.x * 2 + (threadIdx.x >> 7);
    int c = threadIdx.x & 127;
    float x0 = x[node * 3 + 0];
    float x1 = x[node * 3 + 1];
    float x2 = x[node * 3 + 2];
    float acc = x0 * pw[c] + x1 * pw[128 + c] + x2 * pw[256 + c];
    acc += pb[c];
    int dim = c >> 6;
    int inner = c & 63;
    int jj = inner & 31;
    float p = pos[node * 2 + dim];
    float omega = exp2f(-(float)jj * 0.41524101186092027f);
    float ang = p * omega;
    acc += (inner < 32) ? __sinf(ang) : __cosf(ang);
    h[(size_t)node * 128 + c] = acc;
}

// ---------------- degree histogram ----------------
__global__ __launch_bounds__(256) void k_deg(const int* __restrict__ edges, int* __restrict__ deg) {
    int e = blockIdx.x * 256 + threadIdx.x;
    if (e < N_EDGESC) {
        int2 e2 = ((const int2*)edges)[e];
        atomicAdd(&deg[e2.y], 1);
    }
}

// ---------------- exclusive scan (32768 = 1024 threads x 32) ----------------
__global__ __launch_bounds__(1024) void k_scan(const int* __restrict__ deg,
                                               int* __restrict__ off, int* __restrict__ cur,
                                               float* __restrict__ rs, float* __restrict__ bg) {
    __shared__ int ls[1024];
    int tid = threadIdx.x;
    int base = tid * 32;
    int v[32];
    int s = 0;
#pragma unroll
    for (int j = 0; j < 32; j++) { v[j] = deg[base + j]; s += v[j]; }
    ls[tid] = s;
    __syncthreads();
    for (int ofs = 1; ofs < 1024; ofs <<= 1) {
        int t = (tid >= ofs) ? ls[tid - ofs] : 0;
        __syncthreads();
        ls[tid] += t;
        __syncthreads();
    }
    int run = ls[tid] - s;
#pragma unroll
    for (int j = 0; j < 32; j++) {
        off[base + j] = run;
        cur[base + j] = run;
        int d = v[j];
        rs[base + j] = 1.f / (float)(d > 0 ? d : 1);
        bg[base + j] = d > 0 ? 1.f : 0.f;
        run += d;
    }
}

// ---------------- CSR fill (placement order nondeterministic; sorted in accum) ----------------
__global__ __launch_bounds__(256) void k_fill(const int* __restrict__ edges,
                                              int* __restrict__ cur, int* __restrict__ csr) {
    int e = blockIdx.x * 256 + threadIdx.x;
    if (e < N_EDGESC) {
        int2 e2 = ((const int2*)edges)[e];
        int pos = atomicAdd(&cur[e2.y], 1);
        csr[pos] = e2.x;
    }
}

// ---------------- dual-W GEMM: V = A@Wv ; U = A@Wu + bu  (double-buffered W) ----------------
// (r15 version, unchanged — bit-identical)
__global__ __launch_bounds__(256, 2) void gemm_dualw(const float* __restrict__ A,
                                                     const float* __restrict__ Wv,
                                                     const float* __restrict__ Wu,
                                                     const float* __restrict__ bu,
                                                     float* __restrict__ V, float* __restrict__ U) {
    __shared__ float Wsv[2][16 * 128];
    __shared__ float Wsu[2][16 * 128];
    int tid = threadIdx.x;
    int cg = tid & 31;
    int rg = tid >> 5;
    int m0 = blockIdx.x * 32 + rg * 4;
    int c0 = cg * 4;
    const float* Ar = A + (size_t)m0 * 128;

    float accv[4][4], accu[4][4];
#pragma unroll
    for (int r = 0; r < 4; r++)
#pragma unroll
        for (int c = 0; c < 4; c++) { accv[r][c] = 0.f; accu[r][c] = 0.f; }

#define STAGE_DW(buf, kc)                                                          \
    {                                                                              \
        const float4* Wgv = (const float4*)(Wv + (size_t)(kc) * 128);              \
        const float4* Wgu = (const float4*)(Wu + (size_t)(kc) * 128);              \
        float4* Wlv = (float4*)Wsv[buf];                                           \
        float4* Wlu = (float4*)Wsu[buf];                                           \
        _Pragma("unroll") for (int i = 0; i < 2; i++) {                            \
            Wlv[tid + i * 256] = Wgv[tid + i * 256];                               \
            Wlu[tid + i * 256] = Wgu[tid + i * 256];                               \
        }                                                                          \
    }

    STAGE_DW(0, 0)
    __syncthreads();
    for (int c = 0; c < 8; c++) {
        int buf = c & 1;
        if (c + 1 < 8) STAGE_DW(buf ^ 1, (c + 1) * 16)
        int kc = c * 16;
#pragma unroll
        for (int k0 = 0; k0 < 16; k0 += 4) {
            float4 a[4];
#pragma unroll
            for (int r = 0; r < 4; r++) a[r] = *(const float4*)(Ar + r * 128 + kc + k0);
#pragma unroll
            for (int kk = 0; kk < 4; kk++) {
                float4 wv = *(const float4*)(Wsv[buf] + (k0 + kk) * 128 + c0);
                float4 wu = *(const float4*)(Wsu[buf] + (k0 + kk) * 128 + c0);
#pragma unroll
                for (int r = 0; r < 4; r++) {
                    float aa = ((const float*)&a[r])[kk];
                    accv[r][0] += aa * wv.x; accv[r][1] += aa * wv.y;
                    accv[r][2] += aa * wv.z; accv[r][3] += aa * wv.w;
                    accu[r][0] += aa * wu.x; accu[r][1] += aa * wu.y;
                    accu[r][2] += aa * wu.z; accu[r][3] += aa * wu.w;
                }
            }
        }
        __syncthreads();
    }
#undef STAGE_DW
#pragma unroll
    for (int r = 0; r < 4; r++) {
        int row = m0 + r;
        float4 ov, ou;
        ov.x = accv[r][0]; ov.y = accv[r][1]; ov.z = accv[r][2]; ov.w = accv[r][3];
        ou.x = accu[r][0] + bu[c0];
        ou.y = accu[r][1] + bu[c0 + 1];
        ou.z = accu[r][2] + bu[c0 + 2];
        ou.w = accu[r][3] + bu[c0 + 3];
        *(float4*)(V + (size_t)row * 128 + c0) = ov;
        *(float4*)(U + (size_t)row * 128 + c0) = ou;
    }
}

// ---------------- fused post-accum chain, 16-row double-buffered W chunks ----------------
// LDS 32KB (Wc 2x8KB + T 16KB) -> 4 blocks/CU, all 1024 blocks co-resident (no tail).
// FMA order per accumulator k-ascending; epilogues unchanged -> bit-identical to r15.
__global__ __launch_bounds__(256, 2) void gemm_chain(const float* __restrict__ S,
                                                     float* __restrict__ h,
                                                     const float* __restrict__ W2,
                                                     const float* __restrict__ b2,
                                                     const float* __restrict__ rs,
                                                     const float* __restrict__ bg,
                                                     const float* __restrict__ U1a,
                                                     const float* __restrict__ U1b,
                                                     const float* __restrict__ ub1,
                                                     const float* __restrict__ U2,
                                                     const float* __restrict__ ub2,
                                                     const float* __restrict__ wrel,
                                                     const float* __restrict__ wroot,
                                                     float* __restrict__ pout,
                                                     float* __restrict__ rout) {
    __shared__ float Wc[2][16 * 128];   // 2 x 8KB rotating weight chunks
    __shared__ float T[32 * 128];       // 16KB tile: agg, then q
    int tid = threadIdx.x;
    int cg = tid & 31;
    int rg = tid >> 5;
    int m0 = blockIdx.x * 32 + rg * 4;
    int c0 = cg * 4;
    const float* Sr = S + (size_t)m0 * 128;
    const float* hr = h + (size_t)m0 * 128;

    float acc1[4][4], acc2[4][4];

#define ZERO(acc)                                                          \
    {                                                                      \
        _Pragma("unroll") for (int r = 0; r < 4; r++)                      \
            _Pragma("unroll") for (int c = 0; c < 4; c++) acc[r][c] = 0.f; \
    }
#define STAGE_W(buf, Wsrc, kc)                                             \
    {                                                                      \
        const float4* Wg = (const float4*)((Wsrc) + (size_t)(kc) * 128);   \
        float4* Wl = (float4*)Wc[buf];                                     \
        Wl[tid] = Wg[tid];                                                 \
        Wl[tid + 256] = Wg[tid + 256];                                     \
    }
#define COMPUTE_G(acc, buf, Abase, kc)                                     \
    {                                                                      \
        _Pragma("unroll") for (int k0 = 0; k0 < 16; k0 += 4) {             \
            float4 a[4];                                                   \
            _Pragma("unroll") for (int r = 0; r < 4; r++)                  \
                a[r] = *(const float4*)((Abase) + r * 128 + (kc) + k0);    \
            _Pragma("unroll") for (int kk = 0; kk < 4; kk++) {             \
                float4 wv = *(const float4*)(Wc[buf] + (k0 + kk) * 128 + c0); \
                _Pragma("unroll") for (int r = 0; r < 4; r++) {            \
                    float aa = ((const float*)&a[r])[kk];                  \
                    acc[r][0] += aa * wv.x; acc[r][1] += aa * wv.y;        \
                    acc[r][2] += aa * wv.z; acc[r][3] += aa * wv.w;        \
                }                                                          \
            }                                                              \
        }                                                                  \
    }
#define COMPUTE_T(acc, buf, kc)                                            \
    {                                                                      \
        _Pragma("unroll") for (int k0 = 0; k0 < 16; k0 += 4) {             \
            float4 a[4];                                                   \
            _Pragma("unroll") for (int r = 0; r < 4; r++)                  \
                a[r] = *(const float4*)(T + (rg * 4 + r) * 128 + (kc) + k0); \
            _Pragma("unroll") for (int kk = 0; kk < 4; kk++) {             \
                float4 wv = *(const float4*)(Wc[buf] + (k0 + kk) * 128 + c0); \
                _Pragma("unroll") for (int r = 0; r < 4; r++) {            \
                    float aa = ((const float*)&a[r])[kk];                  \
                    acc[r][0] += aa * wv.x; acc[r][1] += aa * wv.y;        \
                    acc[r][2] += aa * wv.z; acc[r][3] += aa * wv.w;        \
                }                                                          \
            }                                                              \
        }                                                                  \
    }
#define PASS_G(acc, Wsrc, Abase)                                           \
    {                                                                      \
        STAGE_W(0, Wsrc, 0)                                                \
        __syncthreads();                                                   \
        _Pragma("unroll") for (int c = 0; c < 8; c++) {                    \
            int buf = c & 1;                                               \
            if (c + 1 < 8) STAGE_W(buf ^ 1, Wsrc, (c + 1) * 16)            \
            COMPUTE_G(acc, buf, Abase, c * 16)                             \
            __syncthreads();                                               \
        }                                                                  \
    }
#define PASS_T(acc, Wsrc)                                                  \
    {                                                                      \
        STAGE_W(0, Wsrc, 0)                                                \
        __syncthreads();                                                   \
        _Pragma("unroll") for (int c = 0; c < 8; c++) {                    \
            int buf = c & 1;                                               \
            if (c + 1 < 8) STAGE_W(buf ^ 1, Wsrc, (c + 1) * 16)            \
            COMPUTE_T(acc, buf, c * 16)                                    \
            __syncthreads();                                               \
        }                                                                  \
    }

    // ---- stage 1: acc1 = S@W2 ; aggT = acc1*rs + b2*bg ----
    ZERO(acc1)
    PASS_G(acc1, W2, Sr)
#pragma unroll
    for (int r = 0; r < 4; r++) {
        int row = m0 + r;
        float rsv = rs[row];
        float bgv = bg[row];
        float4 o;
        float* op = (float*)&o;
#pragma unroll
        for (int c = 0; c < 4; c++) {
            float xv = acc1[r][c];
            xv *= rsv;
            xv += b2[c0 + c] * bgv;
            op[c] = xv;
        }
        *(float4*)(T + (rg * 4 + r) * 128 + c0) = o;
    }
    __syncthreads();   // aggT visible

    // ---- stage 2: acc1 = h@U1a ; acc2 = aggT@U1b ; q = silu(acc1+acc2+ub1) ----
    ZERO(acc1)
    PASS_G(acc1, U1a, hr)
    ZERO(acc2)
    PASS_T(acc2, U1b)
    __syncthreads();   // all reads of aggT done before overwrite
#pragma unroll
    for (int r = 0; r < 4; r++) {
        float4 o;
        float* op = (float*)&o;
#pragma unroll
        for (int c = 0; c < 4; c++) {
            float xv = acc1[r][c];
            xv += acc2[r][c];
            xv += ub1[c0 + c];
            op[c] = siluf(xv);
        }
        *(float4*)(T + (rg * 4 + r) * 128 + c0) = o;
    }
    __syncthreads();   // qT visible

    // ---- stage 3: acc1 = qT@U2 ; h = acc1 + ub2 + h ; p/r dots ----
    ZERO(acc1)
    PASS_T(acc1, U2)
    float prel[4], prot[4];
#pragma unroll
    for (int r = 0; r < 4; r++) {
        int row = m0 + r;
        float4 o;
        float* op = (float*)&o;
#pragma unroll
        for (int c = 0; c < 4; c++) {
            float xv = acc1[r][c];
            xv *= 1.f;
            xv += ub2[c0 + c] * 1.f;
            xv += hr[r * 128 + c0 + c];
            op[c] = xv;
        }
        prel[r] = op[0] * wrel[c0] + op[1] * wrel[c0 + 1] + op[2] * wrel[c0 + 2] + op[3] * wrel[c0 + 3];
        prot[r] = op[0] * wroot[c0] + op[1] * wroot[c0 + 1] + op[2] * wroot[c0 + 2] + op[3] * wroot[c0 + 3];
        *(float4*)(h + (size_t)row * 128 + c0) = o;
    }
#pragma unroll
    for (int r = 0; r < 4; r++) {
        float a = prel[r], b = prot[r];
#pragma unroll
        for (int m = 1; m < 32; m <<= 1) {
            a += __shfl_xor(a, m);
            b += __shfl_xor(b, m);
        }
        if (cg == 0) { pout[m0 + r] = a; rout[m0 + r] = b; }
    }
#undef ZERO
#undef STAGE_W
#undef COMPUTE_G
#undef COMPUTE_T
#undef PASS_G
#undef PASS_T
}

// ---------------- fused sort + accum: wave per node ----------------
// Sorts the CSR segment ascending (128-wide in-reg bitonic, 2 keys/lane; n>128
// fallback), writes sorted csr back (for k_score), then accumulates
// S[d] = sum_e silu(u[d] + v[src_e]) with float2 loads (1 load/edge).
// Per-dim add order = edge-ascending, identical to r15 -> S bitwise identical.
__global__ __launch_bounds__(256) void k_accum_S(const float* __restrict__ v,
                                                 int* __restrict__ csr, const int* __restrict__ off,
                                                 const int* __restrict__ deg, float* S) {
    int d = blockIdx.x * 4 + (threadIdx.x >> 6);
    int lane = threadIdx.x & 63;
    int o = off[d], n = deg[d];
    float* srow = S + (size_t)d * 128;
    float2 u = *(const float2*)(srow + lane * 2);
    float2 a = {0.f, 0.f};

    // ---- sort segment ----
    int key0 = 0x7FFFFFFF, key1 = 0x7FFFFFFF;
    bool small = (n <= 128);
    if (small) {
        if (n > 1) {
            int i0 = 2 * lane, i1 = 2 * lane + 1;
            if (i0 < n) key0 = csr[o + i0];
            if (i1 < n) key1 = csr[o + i1];
            // bitonic over 128 virtual elems: vi = 2*lane + t
            for (int k = 2; k <= 128; k <<= 1) {
                for (int j = k >> 1; j >= 2; j >>= 1) {
                    int p0 = __shfl_xor(key0, j >> 1);
                    int p1 = __shfl_xor(key1, j >> 1);
                    int vi0 = 2 * lane, vi1 = vi0 + 1;
                    bool keep0 = (((vi0 & j) == 0) == ((vi0 & k) == 0));
                    bool keep1 = (((vi1 & j) == 0) == ((vi1 & k) == 0));
                    key0 = keep0 ? min(key0, p0) : max(key0, p0);
                    key1 = keep1 ? min(key1, p1) : max(key1, p1);
                }
                {   // j == 1: local exchange (vi0 even, vi1 odd share (vi&k) for k>=2)
                    bool asc = (((2 * lane) & k) == 0);
                    int lo = min(key0, key1), hi = max(key0, key1);
                    key0 = asc ? lo : hi;
                    key1 = asc ? hi : lo;
                }
            }
            if (2 * lane < n) csr[o + 2 * lane] = key0;
            if (2 * lane + 1 < n) csr[o + 2 * lane + 1] = key1;
        } else if (n == 1) {
            key0 = csr[o];   // no sort needed; load for in-reg use
            key0 = __shfl(key0, 0);
        }
    } else {
        if (lane == 0) {
            for (int i = o + 1; i < o + n; i++) {
                int x = csr[i];
                int j = i - 1;
                while (j >= o && csr[j] > x) { csr[j + 1] = csr[j]; j--; }
                csr[j + 1] = x;
            }
        }
        __threadfence();
    }

    // ---- accumulate ----
    for (int base = 0; base < n; base += 64) {
        int cnt = min(64, n - base);
        int sall;
        if (small) {
            int src = (base + lane) >> 1;
            int e0 = __shfl(key0, src);
            int e1 = __shfl(key1, src);
            sall = (lane & 1) ? e1 : e0;
        } else {
            sall = (lane < cnt) ? csr[o + base + lane] : 0;
        }
        int j = 0;
        for (; j + 8 <= cnt; j += 8) {
            int s0 = __shfl(sall, j + 0), s1 = __shfl(sall, j + 1);
            int s2 = __shfl(sall, j + 2), s3 = __shfl(sall, j + 3);
            int s4 = __shfl(sall, j + 4), s5 = __shfl(sall, j + 5);
            int s6 = __shfl(sall, j + 6), s7 = __shfl(sall, j + 7);
            float2 w0 = *(const float2*)(v + (size_t)s0 * 128 + lane * 2);
            float2 w1 = *(const float2*)(v + (size_t)s1 * 128 + lane * 2);
            float2 w2 = *(const float2*)(v + (size_t)s2 * 128 + lane * 2);
            float2 w3 = *(const float2*)(v + (size_t)s3 * 128 + lane * 2);
            float2 w4 = *(const float2*)(v + (size_t)s4 * 128 + lane * 2);
            float2 w5 = *(const float2*)(v + (size_t)s5 * 128 + lane * 2);
            float2 w6 = *(const float2*)(v + (size_t)s6 * 128 + lane * 2);
            float2 w7 = *(const float2*)(v + (size_t)s7 * 128 + lane * 2);
            a.x += siluf(u.x + w0.x); a.y += siluf(u.y + w0.y);
            a.x += siluf(u.x + w1.x); a.y += siluf(u.y + w1.y);
            a.x += siluf(u.x + w2.x); a.y += siluf(u.y + w2.y);
            a.x += siluf(u.x + w3.x); a.y += siluf(u.y + w3.y);
            a.x += siluf(u.x + w4.x); a.y += siluf(u.y + w4.y);
            a.x += siluf(u.x + w5.x); a.y += siluf(u.y + w5.y);
            a.x += siluf(u.x + w6.x); a.y += siluf(u.y + w6.y);
            a.x += siluf(u.x + w7.x); a.y += siluf(u.y + w7.y);
        }
        for (; j < cnt; j++) {
            int s = __shfl(sall, j);
            float2 w = *(const float2*)(v + (size_t)s * 128 + lane * 2);
            a.x += siluf(u.x + w.x);
            a.y += siluf(u.y + w.y);
        }
    }
    *(float2*)(srow + lane * 2) = a;
}

// ---------------- score[d] = tanh( (sum p[src]) / cnt + rel_b + r[d] ) ----------------
__global__ __launch_bounds__(256) void k_score(const float* __restrict__ p, const float* __restrict__ r,
                                               const int* __restrict__ csr, const int* __restrict__ off,
                                               const int* __restrict__ deg, const float* __restrict__ relb,
                                               float* __restrict__ score) {
    int d = blockIdx.x * 4 + (threadIdx.x >> 6);
    int lane = threadIdx.x & 63;
    int o = off[d], n = deg[d];
    float a = 0.f;
    for (int j = lane; j < n; j += 64) a += p[csr[o + j]];
    for (int m = 32; m > 0; m >>= 1) a += __shfl_xor(a, m);
    if (lane == 0) {
        float cnt = (float)(n > 0 ? n : 1);
        score[d] = tanhf(a / cnt + relb[0] + r[d]);
    }
}

// ---------------- per-graph exact top-k via radix-select + direct ranking ----------------
__global__ __launch_bounds__(1024) void k_topk(const float* __restrict__ score, const float* __restrict__ h,
                                               float* __restrict__ out) {
    __shared__ u32 ms[NPG];
    __shared__ u32 hist[256];
    __shared__ u32 sbuf[1024];
    __shared__ u64 sel[KOUT];
    __shared__ float ordv[KOUT];
    __shared__ int ordi[KOUT];
    __shared__ u32 selCnt, sPrefix, sNeed, sB;

    int g = blockIdx.x;
    int tid = threadIdx.x;

    for (int i = tid; i < NPG; i += 1024) {
        u32 u = __float_as_uint(score[(size_t)g * NPG + i]);
        ms[i] = (u & 0x80000000u) ? ~u : (u | 0x80000000u);
    }
    if (tid == 0) { sNeed = KOUT; sPrefix = 0; selCnt = 0; }
    __syncthreads();

    for (int pass = 0; pass < 4; pass++) {
        int shift = 24 - pass * 8;
        if (tid < 256) hist[tid] = 0;
        __syncthreads();
        u32 pfx = sPrefix;
        for (int i = tid; i < NPG; i += 1024) {
            u32 v = ms[i];
            if (pass == 0 || (v >> (shift + 8)) == pfx)
                atomicAdd(&hist[(v >> shift) & 255u], 1u);
        }
        __syncthreads();
        if (tid < 256) sbuf[tid] = hist[tid];
        __syncthreads();
        for (int ofs = 1; ofs < 256; ofs <<= 1) {
            u32 t = 0;
            if (tid < 256 && tid + ofs < 256) t = sbuf[tid + ofs];
            __syncthreads();
            if (tid < 256) sbuf[tid] += t;
            __syncthreads();
        }
        u32 need = sNeed;
        if (tid < 256) {
            if (sbuf[tid] >= need && (tid == 255 || sbuf[tid + 1] < need)) sB = (u32)tid;
        }
        __syncthreads();
        if (tid == 0) {
            u32 B = sB;
            u32 above = (B == 255) ? 0u : sbuf[B + 1];
            sNeed = need - above;
            sPrefix = (sPrefix << 8) | B;
        }
        __syncthreads();
    }
    u32 T = sPrefix;
    u32 rTie = sNeed;

    int base = tid * 8;
    u32 lc = 0;
#pragma unroll
    for (int j = 0; j < 8; j++) lc += (ms[base + j] == T);
    __syncthreads();
    sbuf[tid] = lc;
    __syncthreads();
    u32 own = lc;
    for (int ofs = 1; ofs < 1024; ofs <<= 1) {
        u32 t = (tid >= ofs) ? sbuf[tid - ofs] : 0;
        __syncthreads();
        sbuf[tid] += t;
        __syncthreads();
    }
    u32 excl = sbuf[tid] - own;

#pragma unroll
    for (int j = 0; j < 8; j++) {
        int i = base + j;
        u32 v = ms[i];
        bool pick = (v > T) || ((v == T) && (excl < rTie));
        if (v == T) excl++;
        if (pick) {
            u32 slot = atomicAdd(&selCnt, 1u);
            sel[slot] = ((u64)v << 32) | (u32)(NPG - 1 - i);
        }
    }
    __syncthreads();

    if (tid < KOUT) {
        u64 mine = sel[tid];
        int rank = 0;
        for (int j = 0; j < KOUT; j++) rank += (sel[j] > mine);
        u32 v = (u32)(mine >> 32);
        int idx = NPG - 1 - (int)(mine & 0xFFFFFFFFu);
        u32 uu = (v & 0x80000000u) ? (v & 0x7FFFFFFFu) : ~v;
        ordv[rank] = __uint_as_float(uu);
        ordi[rank] = idx;
    }
    __syncthreads();

    for (int t = tid; t < KOUT * 128; t += 1024) {
        int r = t >> 7, c = t & 127;
        int node = g * NPG + ordi[r];
        out[((size_t)g * KOUT + r) * 128 + c] = h[(size_t)node * 128 + c] * ordv[r];
    }
    for (int t = tid; t < KOUT; t += 1024)
        out[(size_t)4 * KOUT * 128 + (size_t)g * KOUT + t] = (float)g;
}

extern "C" void kernel_launch(void* const* d_in, const int* in_sizes, int n_in,
                              void* d_out, int out_size, void* d_ws, size_t ws_size,
                              hipStream_t stream) {
    const float* x        = (const float*)d_in[0];
    const float* mesh_pos = (const float*)d_in[1];
    const int*   edges    = (const int*)d_in[2];
    const float* proj_w   = (const float*)d_in[4];
    const float* proj_b   = (const float*)d_in[5];
    const float* msg_w1   = (const float*)d_in[6];
    const float* msg_b1   = (const float*)d_in[7];
    const float* msg_w2   = (const float*)d_in[8];
    const float* msg_b2   = (const float*)d_in[9];
    const float* upd_w1   = (const float*)d_in[10];
    const float* upd_b1   = (const float*)d_in[11];
    const float* upd_w2   = (const float*)d_in[12];
    const float* upd_b2   = (const float*)d_in[13];
    const float* pool_rel_w  = (const float*)d_in[14];
    const float* pool_rel_b  = (const float*)d_in[15];
    const float* pool_root_w = (const float*)d_in[16];
    float* out = (float*)d_out;

    // workspace: 3 x 16MB node buffers + small arrays (~51.1MB)
    char* w = (char*)d_ws;
    float* h  = (float*)(w);                   // h0 -> h_new (in place)
    float* v  = (float*)(w + (1ull << 24));    // v (dead after accum)
    float* S  = (float*)(w + (2ull << 24));    // u -> S
    char* sm  = w + (3ull << 24);
    int*   deg   = (int*)(sm);
    int*   off   = (int*)(sm + 131072);
    int*   cur   = (int*)(sm + 262144);
    float* rsA   = (float*)(sm + 393216);
    float* bgA   = (float*)(sm + 524288);
    float* pp    = (float*)(sm + 655360);
    float* rr    = (float*)(sm + 786432);
    float* score = (float*)(sm + 917504);
    int*   csr   = (int*)(sm + 1048576);       // 2MB

    k_h0<<<N_NODESC / 2, 256, 0, stream>>>(x, mesh_pos, proj_w, proj_b, h, deg);
    k_deg<<<N_EDGESC / 256, 256, 0, stream>>>(edges, deg);
    k_scan<<<1, 1024, 0, stream>>>(deg, off, cur, rsA, bgA);
    k_fill<<<N_EDGESC / 256, 256, 0, stream>>>(edges, cur, csr);

    // v = h@W1b ; S = h@W1a + b1   (one pass over h)
    gemm_dualw<<<1024, 256, 0, stream>>>(h, msg_w1 + 128 * 128, msg_w1, msg_b1, v, S);
    // sort csr segments + S[d] = sum_e silu( S[d] + v[src_e] )   (in place)
    k_accum_S<<<N_NODESC / 4, 256, 0, stream>>>(v, csr, off, deg, S);
    // fused: agg = (S@W2)*rs + b2*bg ; q = silu(h@U1a + agg@U1b + ub1) ;
    //        h = h + q@U2 + ub2 ; p/r dots
    gemm_chain<<<1024, 256, 0, stream>>>(S, h, msg_w2, msg_b2, rsA, bgA,
                                         upd_w1, upd_w1 + 128 * 128, upd_b1,
                                         upd_w2, upd_b2,
                                         pool_rel_w, pool_root_w, pp, rr);

    k_score<<<N_NODESC / 4, 256, 0, stream>>>(pp, rr, csr, off, deg, pool_rel_b, score);
    k_topk<<<4, 1024, 0, stream>>>(score, h, out);
}

// Round 17
// 372.678 us; speedup vs baseline: 1.0734x; 1.0734x over previous
//
#include <hip/hip_runtime.h>
#include <hip/hip_bf16.h>
#include <math.h>

#define N_NODESC 32768
#define N_EDGESC 524288
#define NPG 8192
#define KOUT 512

typedef unsigned short u16;
typedef unsigned int u32;
typedef unsigned long long u64;

__device__ __forceinline__ float siluf(float x) {
    return x / (1.f + __expf(-x));
}

// ---------------- h0 = x@proj_w + proj_b + sincos(mesh_pos)  (+ zero deg) ----------------
__global__ __launch_bounds__(256) void k_h0(const float* __restrict__ x,
                                            const float* __restrict__ pos,
                                            const float* __restrict__ pw,
                                            const float* __restrict__ pb,
                                            float* __restrict__ h,
                                            int* __restrict__ deg) {
    int gid = blockIdx.x * 256 + threadIdx.x;
    if (gid < N_NODESC) deg[gid] = 0;
    int node = blockIdx.x * 2 + (threadIdx.x >> 7);
    int c = threadIdx.x & 127;
    float x0 = x[node * 3 + 0];
    float x1 = x[node * 3 + 1];
    float x2 = x[node * 3 + 2];
    float acc = x0 * pw[c] + x1 * pw[128 + c] + x2 * pw[256 + c];
    acc += pb[c];
    int dim = c >> 6;
    int inner = c & 63;
    int jj = inner & 31;
    float p = pos[node * 2 + dim];
    float omega = exp2f(-(float)jj * 0.41524101186092027f);
    float ang = p * omega;
    acc += (inner < 32) ? __sinf(ang) : __cosf(ang);
    h[(size_t)node * 128 + c] = acc;
}

// ---------------- degree histogram ----------------
__global__ __launch_bounds__(256) void k_deg(const int* __restrict__ edges, int* __restrict__ deg) {
    int e = blockIdx.x * 256 + threadIdx.x;
    if (e < N_EDGESC) {
        int2 e2 = ((const int2*)edges)[e];
        atomicAdd(&deg[e2.y], 1);
    }
}

// ---------------- exclusive scan (32768 = 1024 threads x 32) ----------------
__global__ __launch_bounds__(1024) void k_scan(const int* __restrict__ deg,
                                               int* __restrict__ off, int* __restrict__ cur,
                                               float* __restrict__ rs, float* __restrict__ bg) {
    __shared__ int ls[1024];
    int tid = threadIdx.x;
    int base = tid * 32;
    int v[32];
    int s = 0;
#pragma unroll
    for (int j = 0; j < 32; j++) { v[j] = deg[base + j]; s += v[j]; }
    ls[tid] = s;
    __syncthreads();
    for (int ofs = 1; ofs < 1024; ofs <<= 1) {
        int t = (tid >= ofs) ? ls[tid - ofs] : 0;
        __syncthreads();
        ls[tid] += t;
        __syncthreads();
    }
    int run = ls[tid] - s;
#pragma unroll
    for (int j = 0; j < 32; j++) {
        off[base + j] = run;
        cur[base + j] = run;
        int d = v[j];
        rs[base + j] = 1.f / (float)(d > 0 ? d : 1);
        bg[base + j] = d > 0 ? 1.f : 0.f;
        run += d;
    }
}

// ---------------- CSR fill (placement order nondeterministic; sorted in accum) ----------------
__global__ __launch_bounds__(256) void k_fill(const int* __restrict__ edges,
                                              int* __restrict__ cur, int* __restrict__ csr) {
    int e = blockIdx.x * 256 + threadIdx.x;
    if (e < N_EDGESC) {
        int2 e2 = ((const int2*)edges)[e];
        int pos = atomicAdd(&cur[e2.y], 1);
        csr[pos] = e2.x;
    }
}

// ---------------- dual-W GEMM: V = A@Wv ; U = A@Wu + bu  (double-buffered W) ----------------
__global__ __launch_bounds__(256, 2) void gemm_dualw(const float* __restrict__ A,
                                                     const float* __restrict__ Wv,
                                                     const float* __restrict__ Wu,
                                                     const float* __restrict__ bu,
                                                     float* __restrict__ V, float* __restrict__ U) {
    __shared__ float Wsv[2][16 * 128];
    __shared__ float Wsu[2][16 * 128];
    int tid = threadIdx.x;
    int cg = tid & 31;
    int rg = tid >> 5;
    int m0 = blockIdx.x * 32 + rg * 4;
    int c0 = cg * 4;
    const float* Ar = A + (size_t)m0 * 128;

    float accv[4][4], accu[4][4];
#pragma unroll
    for (int r = 0; r < 4; r++)
#pragma unroll
        for (int c = 0; c < 4; c++) { accv[r][c] = 0.f; accu[r][c] = 0.f; }

#define STAGE_DW(buf, kc)                                                          \
    {                                                                              \
        const float4* Wgv = (const float4*)(Wv + (size_t)(kc) * 128);              \
        const float4* Wgu = (const float4*)(Wu + (size_t)(kc) * 128);              \
        float4* Wlv = (float4*)Wsv[buf];                                           \
        float4* Wlu = (float4*)Wsu[buf];                                           \
        _Pragma("unroll") for (int i = 0; i < 2; i++) {                            \
            Wlv[tid + i * 256] = Wgv[tid + i * 256];                               \
            Wlu[tid + i * 256] = Wgu[tid + i * 256];                               \
        }                                                                          \
    }

    STAGE_DW(0, 0)
    __syncthreads();
    for (int c = 0; c < 8; c++) {
        int buf = c & 1;
        if (c + 1 < 8) STAGE_DW(buf ^ 1, (c + 1) * 16)
        int kc = c * 16;
#pragma unroll
        for (int k0 = 0; k0 < 16; k0 += 4) {
            float4 a[4];
#pragma unroll
            for (int r = 0; r < 4; r++) a[r] = *(const float4*)(Ar + r * 128 + kc + k0);
#pragma unroll
            for (int kk = 0; kk < 4; kk++) {
                float4 wv = *(const float4*)(Wsv[buf] + (k0 + kk) * 128 + c0);
                float4 wu = *(const float4*)(Wsu[buf] + (k0 + kk) * 128 + c0);
#pragma unroll
                for (int r = 0; r < 4; r++) {
                    float aa = ((const float*)&a[r])[kk];
                    accv[r][0] += aa * wv.x; accv[r][1] += aa * wv.y;
                    accv[r][2] += aa * wv.z; accv[r][3] += aa * wv.w;
                    accu[r][0] += aa * wu.x; accu[r][1] += aa * wu.y;
                    accu[r][2] += aa * wu.z; accu[r][3] += aa * wu.w;
                }
            }
        }
        __syncthreads();
    }
#undef STAGE_DW
#pragma unroll
    for (int r = 0; r < 4; r++) {
        int row = m0 + r;
        float4 ov, ou;
        ov.x = accv[r][0]; ov.y = accv[r][1]; ov.z = accv[r][2]; ov.w = accv[r][3];
        ou.x = accu[r][0] + bu[c0];
        ou.y = accu[r][1] + bu[c0 + 1];
        ou.z = accu[r][2] + bu[c0 + 2];
        ou.w = accu[r][3] + bu[c0 + 3];
        *(float4*)(V + (size_t)row * 128 + c0) = ov;
        *(float4*)(U + (size_t)row * 128 + c0) = ou;
    }
}

// ---------------- fused post-accum chain, 32-row double-buffered W chunks (r15) ----------------
// stage1: aggT = (S@W2)*rs + b2*bg ; stage2: q = silu(h@U1a + aggT@U1b + ub1) ;
// stage3: h = h + qT@U2 + ub2 + p/r dots. 2x16KB W ping-pong + 16KB T = 48KB LDS.
__global__ __launch_bounds__(256, 2) void gemm_chain(const float* __restrict__ S,
                                                     float* __restrict__ h,
                                                     const float* __restrict__ W2,
                                                     const float* __restrict__ b2,
                                                     const float* __restrict__ rs,
                                                     const float* __restrict__ bg,
                                                     const float* __restrict__ U1a,
                                                     const float* __restrict__ U1b,
                                                     const float* __restrict__ ub1,
                                                     const float* __restrict__ U2,
                                                     const float* __restrict__ ub2,
                                                     const float* __restrict__ wrel,
                                                     const float* __restrict__ wroot,
                                                     float* __restrict__ pout,
                                                     float* __restrict__ rout) {
    __shared__ float Wc[2][32 * 128];   // 2 x 16KB rotating weight chunks
    __shared__ float T[32 * 128];       // 16KB tile: agg, then q
    int tid = threadIdx.x;
    int cg = tid & 31;
    int rg = tid >> 5;
    int m0 = blockIdx.x * 32 + rg * 4;
    int c0 = cg * 4;
    const float* Sr = S + (size_t)m0 * 128;
    const float* hr = h + (size_t)m0 * 128;

    float acc1[4][4], acc2[4][4];

#define ZERO(acc)                                                          \
    {                                                                      \
        _Pragma("unroll") for (int r = 0; r < 4; r++)                      \
            _Pragma("unroll") for (int c = 0; c < 4; c++) acc[r][c] = 0.f; \
    }
#define STAGE_W(buf, Wsrc, kc)                                             \
    {                                                                      \
        const float4* Wg = (const float4*)((Wsrc) + (size_t)(kc) * 128);   \
        float4* Wl = (float4*)Wc[buf];                                     \
        _Pragma("unroll") for (int i = 0; i < 4; i++)                      \
            Wl[tid + i * 256] = Wg[tid + i * 256];                         \
    }
#define COMPUTE_G(acc, buf, Abase, kc)                                     \
    {                                                                      \
        _Pragma("unroll") for (int k0 = 0; k0 < 32; k0 += 4) {             \
            float4 a[4];                                                   \
            _Pragma("unroll") for (int r = 0; r < 4; r++)                  \
                a[r] = *(const float4*)((Abase) + r * 128 + (kc) + k0);    \
            _Pragma("unroll") for (int kk = 0; kk < 4; kk++) {             \
                float4 wv = *(const float4*)(Wc[buf] + (k0 + kk) * 128 + c0); \
                _Pragma("unroll") for (int r = 0; r < 4; r++) {            \
                    float aa = ((const float*)&a[r])[kk];                  \
                    acc[r][0] += aa * wv.x; acc[r][1] += aa * wv.y;        \
                    acc[r][2] += aa * wv.z; acc[r][3] += aa * wv.w;        \
                }                                                          \
            }                                                              \
        }                                                                  \
    }
#define COMPUTE_T(acc, buf, kc)                                            \
    {                                                                      \
        _Pragma("unroll") for (int k0 = 0; k0 < 32; k0 += 4) {             \
            float4 a[4];                                                   \
            _Pragma("unroll") for (int r = 0; r < 4; r++)                  \
                a[r] = *(const float4*)(T + (rg * 4 + r) * 128 + (kc) + k0); \
            _Pragma("unroll") for (int kk = 0; kk < 4; kk++) {             \
                float4 wv = *(const float4*)(Wc[buf] + (k0 + kk) * 128 + c0); \
                _Pragma("unroll") for (int r = 0; r < 4; r++) {            \
                    float aa = ((const float*)&a[r])[kk];                  \
                    acc[r][0] += aa * wv.x; acc[r][1] += aa * wv.y;        \
                    acc[r][2] += aa * wv.z; acc[r][3] += aa * wv.w;        \
                }                                                          \
            }                                                              \
        }                                                                  \
    }
#define PASS_G(acc, Wsrc, Abase)                                           \
    {                                                                      \
        STAGE_W(0, Wsrc, 0)                                                \
        __syncthreads();                                                   \
        _Pragma("unroll") for (int c = 0; c < 4; c++) {                    \
            int buf = c & 1;                                               \
            if (c + 1 < 4) STAGE_W(buf ^ 1, Wsrc, (c + 1) * 32)            \
            COMPUTE_G(acc, buf, Abase, c * 32)                             \
            __syncthreads();                                               \
        }                                                                  \
    }
#define PASS_T(acc, Wsrc)                                                  \
    {                                                                      \
        STAGE_W(0, Wsrc, 0)                                                \
        __syncthreads();                                                   \
        _Pragma("unroll") for (int c = 0; c < 4; c++) {                    \
            int buf = c & 1;                                               \
            if (c + 1 < 4) STAGE_W(buf ^ 1, Wsrc, (c + 1) * 32)            \
            COMPUTE_T(acc, buf, c * 32)                                    \
            __syncthreads();                                               \
        }                                                                  \
    }

    // ---- stage 1: acc1 = S@W2 ; aggT = acc1*rs + b2*bg ----
    ZERO(acc1)
    PASS_G(acc1, W2, Sr)
#pragma unroll
    for (int r = 0; r < 4; r++) {
        int row = m0 + r;
        float rsv = rs[row];
        float bgv = bg[row];
        float4 o;
        float* op = (float*)&o;
#pragma unroll
        for (int c = 0; c < 4; c++) {
            float xv = acc1[r][c];
            xv *= rsv;
            xv += b2[c0 + c] * bgv;
            op[c] = xv;
        }
        *(float4*)(T + (rg * 4 + r) * 128 + c0) = o;
    }
    __syncthreads();   // aggT visible

    // ---- stage 2: acc1 = h@U1a ; acc2 = aggT@U1b ; q = silu(acc1+acc2+ub1) ----
    ZERO(acc1)
    PASS_G(acc1, U1a, hr)
    ZERO(acc2)
    PASS_T(acc2, U1b)
    __syncthreads();   // all reads of aggT done before overwrite
#pragma unroll
    for (int r = 0; r < 4; r++) {
        float4 o;
        float* op = (float*)&o;
#pragma unroll
        for (int c = 0; c < 4; c++) {
            float xv = acc1[r][c];
            xv += acc2[r][c];
            xv += ub1[c0 + c];
            op[c] = siluf(xv);
        }
        *(float4*)(T + (rg * 4 + r) * 128 + c0) = o;
    }
    __syncthreads();   // qT visible

    // ---- stage 3: acc1 = qT@U2 ; h = acc1 + ub2 + h ; p/r dots ----
    ZERO(acc1)
    PASS_T(acc1, U2)
    float prel[4], prot[4];
#pragma unroll
    for (int r = 0; r < 4; r++) {
        int row = m0 + r;
        float4 o;
        float* op = (float*)&o;
#pragma unroll
        for (int c = 0; c < 4; c++) {
            float xv = acc1[r][c];
            xv *= 1.f;
            xv += ub2[c0 + c] * 1.f;
            xv += hr[r * 128 + c0 + c];
            op[c] = xv;
        }
        prel[r] = op[0] * wrel[c0] + op[1] * wrel[c0 + 1] + op[2] * wrel[c0 + 2] + op[3] * wrel[c0 + 3];
        prot[r] = op[0] * wroot[c0] + op[1] * wroot[c0 + 1] + op[2] * wroot[c0 + 2] + op[3] * wroot[c0 + 3];
        *(float4*)(h + (size_t)row * 128 + c0) = o;
    }
#pragma unroll
    for (int r = 0; r < 4; r++) {
        float a = prel[r], b = prot[r];
#pragma unroll
        for (int m = 1; m < 32; m <<= 1) {
            a += __shfl_xor(a, m);
            b += __shfl_xor(b, m);
        }
        if (cg == 0) { pout[m0 + r] = a; rout[m0 + r] = b; }
    }
#undef ZERO
#undef STAGE_W
#undef COMPUTE_G
#undef COMPUTE_T
#undef PASS_G
#undef PASS_T
}

// ---------------- fused sort + accum: wave per node (r16, kept — saved ~23 µs) ----------------
__global__ __launch_bounds__(256) void k_accum_S(const float* __restrict__ v,
                                                 int* __restrict__ csr, const int* __restrict__ off,
                                                 const int* __restrict__ deg, float* S) {
    int d = blockIdx.x * 4 + (threadIdx.x >> 6);
    int lane = threadIdx.x & 63;
    int o = off[d], n = deg[d];
    float* srow = S + (size_t)d * 128;
    float2 u = *(const float2*)(srow + lane * 2);
    float2 a = {0.f, 0.f};

    // ---- sort segment ----
    int key0 = 0x7FFFFFFF, key1 = 0x7FFFFFFF;
    bool small = (n <= 128);
    if (small) {
        if (n > 1) {
            int i0 = 2 * lane, i1 = 2 * lane + 1;
            if (i0 < n) key0 = csr[o + i0];
            if (i1 < n) key1 = csr[o + i1];
            for (int k = 2; k <= 128; k <<= 1) {
                for (int j = k >> 1; j >= 2; j >>= 1) {
                    int p0 = __shfl_xor(key0, j >> 1);
                    int p1 = __shfl_xor(key1, j >> 1);
                    int vi0 = 2 * lane, vi1 = vi0 + 1;
                    bool keep0 = (((vi0 & j) == 0) == ((vi0 & k) == 0));
                    bool keep1 = (((vi1 & j) == 0) == ((vi1 & k) == 0));
                    key0 = keep0 ? min(key0, p0) : max(key0, p0);
                    key1 = keep1 ? min(key1, p1) : max(key1, p1);
                }
                {
                    bool asc = (((2 * lane) & k) == 0);
                    int lo = min(key0, key1), hi = max(key0, key1);
                    key0 = asc ? lo : hi;
                    key1 = asc ? hi : lo;
                }
            }
            if (2 * lane < n) csr[o + 2 * lane] = key0;
            if (2 * lane + 1 < n) csr[o + 2 * lane + 1] = key1;
        } else if (n == 1) {
            key0 = csr[o];
            key0 = __shfl(key0, 0);
        }
    } else {
        if (lane == 0) {
            for (int i = o + 1; i < o + n; i++) {
                int x = csr[i];
                int j = i - 1;
                while (j >= o && csr[j] > x) { csr[j + 1] = csr[j]; j--; }
                csr[j + 1] = x;
            }
        }
        __threadfence();
    }

    // ---- accumulate ----
    for (int base = 0; base < n; base += 64) {
        int cnt = min(64, n - base);
        int sall;
        if (small) {
            int src = (base + lane) >> 1;
            int e0 = __shfl(key0, src);
            int e1 = __shfl(key1, src);
            sall = (lane & 1) ? e1 : e0;
        } else {
            sall = (lane < cnt) ? csr[o + base + lane] : 0;
        }
        int j = 0;
        for (; j + 8 <= cnt; j += 8) {
            int s0 = __shfl(sall, j + 0), s1 = __shfl(sall, j + 1);
            int s2 = __shfl(sall, j + 2), s3 = __shfl(sall, j + 3);
            int s4 = __shfl(sall, j + 4), s5 = __shfl(sall, j + 5);
            int s6 = __shfl(sall, j + 6), s7 = __shfl(sall, j + 7);
            float2 w0 = *(const float2*)(v + (size_t)s0 * 128 + lane * 2);
            float2 w1 = *(const float2*)(v + (size_t)s1 * 128 + lane * 2);
            float2 w2 = *(const float2*)(v + (size_t)s2 * 128 + lane * 2);
            float2 w3 = *(const float2*)(v + (size_t)s3 * 128 + lane * 2);
            float2 w4 = *(const float2*)(v + (size_t)s4 * 128 + lane * 2);
            float2 w5 = *(const float2*)(v + (size_t)s5 * 128 + lane * 2);
            float2 w6 = *(const float2*)(v + (size_t)s6 * 128 + lane * 2);
            float2 w7 = *(const float2*)(v + (size_t)s7 * 128 + lane * 2);
            a.x += siluf(u.x + w0.x); a.y += siluf(u.y + w0.y);
            a.x += siluf(u.x + w1.x); a.y += siluf(u.y + w1.y);
            a.x += siluf(u.x + w2.x); a.y += siluf(u.y + w2.y);
            a.x += siluf(u.x + w3.x); a.y += siluf(u.y + w3.y);
            a.x += siluf(u.x + w4.x); a.y += siluf(u.y + w4.y);
            a.x += siluf(u.x + w5.x); a.y += siluf(u.y + w5.y);
            a.x += siluf(u.x + w6.x); a.y += siluf(u.y + w6.y);
            a.x += siluf(u.x + w7.x); a.y += siluf(u.y + w7.y);
        }
        for (; j < cnt; j++) {
            int s = __shfl(sall, j);
            float2 w = *(const float2*)(v + (size_t)s * 128 + lane * 2);
            a.x += siluf(u.x + w.x);
            a.y += siluf(u.y + w.y);
        }
    }
    *(float2*)(srow + lane * 2) = a;
}

// ---------------- score[d] = tanh( (sum p[src]) / cnt + rel_b + r[d] ) ----------------
__global__ __launch_bounds__(256) void k_score(const float* __restrict__ p, const float* __restrict__ r,
                                               const int* __restrict__ csr, const int* __restrict__ off,
                                               const int* __restrict__ deg, const float* __restrict__ relb,
                                               float* __restrict__ score) {
    int d = blockIdx.x * 4 + (threadIdx.x >> 6);
    int lane = threadIdx.x & 63;
    int o = off[d], n = deg[d];
    float a = 0.f;
    for (int j = lane; j < n; j += 64) a += p[csr[o + j]];
    for (int m = 32; m > 0; m >>= 1) a += __shfl_xor(a, m);
    if (lane == 0) {
        float cnt = (float)(n > 0 ? n : 1);
        score[d] = tanhf(a / cnt + relb[0] + r[d]);
    }
}

// ---------------- per-graph exact top-k via radix-select + direct ranking ----------------
__global__ __launch_bounds__(1024) void k_topk(const float* __restrict__ score, const float* __restrict__ h,
                                               float* __restrict__ out) {
    __shared__ u32 ms[NPG];
    __shared__ u32 hist[256];
    __shared__ u32 sbuf[1024];
    __shared__ u64 sel[KOUT];
    __shared__ float ordv[KOUT];
    __shared__ int ordi[KOUT];
    __shared__ u32 selCnt, sPrefix, sNeed, sB;

    int g = blockIdx.x;
    int tid = threadIdx.x;

    for (int i = tid; i < NPG; i += 1024) {
        u32 u = __float_as_uint(score[(size_t)g * NPG + i]);
        ms[i] = (u & 0x80000000u) ? ~u : (u | 0x80000000u);
    }
    if (tid == 0) { sNeed = KOUT; sPrefix = 0; selCnt = 0; }
    __syncthreads();

    for (int pass = 0; pass < 4; pass++) {
        int shift = 24 - pass * 8;
        if (tid < 256) hist[tid] = 0;
        __syncthreads();
        u32 pfx = sPrefix;
        for (int i = tid; i < NPG; i += 1024) {
            u32 v = ms[i];
            if (pass == 0 || (v >> (shift + 8)) == pfx)
                atomicAdd(&hist[(v >> shift) & 255u], 1u);
        }
        __syncthreads();
        if (tid < 256) sbuf[tid] = hist[tid];
        __syncthreads();
        for (int ofs = 1; ofs < 256; ofs <<= 1) {
            u32 t = 0;
            if (tid < 256 && tid + ofs < 256) t = sbuf[tid + ofs];
            __syncthreads();
            if (tid < 256) sbuf[tid] += t;
            __syncthreads();
        }
        u32 need = sNeed;
        if (tid < 256) {
            if (sbuf[tid] >= need && (tid == 255 || sbuf[tid + 1] < need)) sB = (u32)tid;
        }
        __syncthreads();
        if (tid == 0) {
            u32 B = sB;
            u32 above = (B == 255) ? 0u : sbuf[B + 1];
            sNeed = need - above;
            sPrefix = (sPrefix << 8) | B;
        }
        __syncthreads();
    }
    u32 T = sPrefix;
    u32 rTie = sNeed;

    int base = tid * 8;
    u32 lc = 0;
#pragma unroll
    for (int j = 0; j < 8; j++) lc += (ms[base + j] == T);
    __syncthreads();
    sbuf[tid] = lc;
    __syncthreads();
    u32 own = lc;
    for (int ofs = 1; ofs < 1024; ofs <<= 1) {
        u32 t = (tid >= ofs) ? sbuf[tid - ofs] : 0;
        __syncthreads();
        sbuf[tid] += t;
        __syncthreads();
    }
    u32 excl = sbuf[tid] - own;

#pragma unroll
    for (int j = 0; j < 8; j++) {
        int i = base + j;
        u32 v = ms[i];
        bool pick = (v > T) || ((v == T) && (excl < rTie));
        if (v == T) excl++;
        if (pick) {
            u32 slot = atomicAdd(&selCnt, 1u);
            sel[slot] = ((u64)v << 32) | (u32)(NPG - 1 - i);
        }
    }
    __syncthreads();

    if (tid < KOUT) {
        u64 mine = sel[tid];
        int rank = 0;
        for (int j = 0; j < KOUT; j++) rank += (sel[j] > mine);
        u32 v = (u32)(mine >> 32);
        int idx = NPG - 1 - (int)(mine & 0xFFFFFFFFu);
        u32 uu = (v & 0x80000000u) ? (v & 0x7FFFFFFFu) : ~v;
        ordv[rank] = __uint_as_float(uu);
        ordi[rank] = idx;
    }
    __syncthreads();

    for (int t = tid; t < KOUT * 128; t += 1024) {
        int r = t >> 7, c = t & 127;
        int node = g * NPG + ordi[r];
        out[((size_t)g * KOUT + r) * 128 + c] = h[(size_t)node * 128 + c] * ordv[r];
    }
    for (int t = tid; t < KOUT; t += 1024)
        out[(size_t)4 * KOUT * 128 + (size_t)g * KOUT + t] = (float)g;
}

extern "C" void kernel_launch(void* const* d_in, const int* in_sizes, int n_in,
                              void* d_out, int out_size, void* d_ws, size_t ws_size,
                              hipStream_t stream) {
    const float* x        = (const float*)d_in[0];
    const float* mesh_pos = (const float*)d_in[1];
    const int*   edges    = (const int*)d_in[2];
    const float* proj_w   = (const float*)d_in[4];
    const float* proj_b   = (const float*)d_in[5];
    const float* msg_w1   = (const float*)d_in[6];
    const float* msg_b1   = (const float*)d_in[7];
    const float* msg_w2   = (const float*)d_in[8];
    const float* msg_b2   = (const float*)d_in[9];
    const float* upd_w1   = (const float*)d_in[10];
    const float* upd_b1   = (const float*)d_in[11];
    const float* upd_w2   = (const float*)d_in[12];
    const float* upd_b2   = (const float*)d_in[13];
    const float* pool_rel_w  = (const float*)d_in[14];
    const float* pool_rel_b  = (const float*)d_in[15];
    const float* pool_root_w = (const float*)d_in[16];
    float* out = (float*)d_out;

    // workspace: 3 x 16MB node buffers + small arrays (~51.1MB)
    char* w = (char*)d_ws;
    float* h  = (float*)(w);                   // h0 -> h_new (in place)
    float* v  = (float*)(w + (1ull << 24));    // v (dead after accum)
    float* S  = (float*)(w + (2ull << 24));    // u -> S
    char* sm  = w + (3ull << 24);
    int*   deg   = (int*)(sm);
    int*   off   = (int*)(sm + 131072);
    int*   cur   = (int*)(sm + 262144);
    float* rsA   = (float*)(sm + 393216);
    float* bgA   = (float*)(sm + 524288);
    float* pp    = (float*)(sm + 655360);
    float* rr    = (float*)(sm + 786432);
    float* score = (float*)(sm + 917504);
    int*   csr   = (int*)(sm + 1048576);       // 2MB

    k_h0<<<N_NODESC / 2, 256, 0, stream>>>(x, mesh_pos, proj_w, proj_b, h, deg);
    k_deg<<<N_EDGESC / 256, 256, 0, stream>>>(edges, deg);
    k_scan<<<1, 1024, 0, stream>>>(deg, off, cur, rsA, bgA);
    k_fill<<<N_EDGESC / 256, 256, 0, stream>>>(edges, cur, csr);

    // v = h@W1b ; S = h@W1a + b1   (one pass over h)
    gemm_dualw<<<1024, 256, 0, stream>>>(h, msg_w1 + 128 * 128, msg_w1, msg_b1, v, S);
    // sort csr segments + S[d] = sum_e silu( S[d] + v[src_e] )   (in place)
    k_accum_S<<<N_NODESC / 4, 256, 0, stream>>>(v, csr, off, deg, S);
    // fused: agg = (S@W2)*rs + b2*bg ; q = silu(h@U1a + agg@U1b + ub1) ;
    //        h = h + q@U2 + ub2 ; p/r dots
    gemm_chain<<<1024, 256, 0, stream>>>(S, h, msg_w2, msg_b2, rsA, bgA,
                                         upd_w1, upd_w1 + 128 * 128, upd_b1,
                                         upd_w2, upd_b2,
                                         pool_rel_w, pool_root_w, pp, rr);

    k_score<<<N_NODESC / 4, 256, 0, stream>>>(pp, rr, csr, off, deg, pool_rel_b, score);
    k_topk<<<4, 1024, 0, stream>>>(score, h, out);
}

// Round 18
// 365.908 us; speedup vs baseline: 1.0933x; 1.0185x over previous
//
#include <hip/hip_runtime.h>
#include <hip/hip_bf16.h>
#include <math.h>

#define N_NODESC 32768
#define N_EDGESC 524288
#define NPG 8192
#define KOUT 512

typedef unsigned short u16;
typedef unsigned int u32;
typedef unsigned long long u64;

__device__ __forceinline__ float siluf(float x) {
    return x / (1.f + __expf(-x));
}

// ---------------- h0 = x@proj_w + proj_b + sincos(mesh_pos)  (+ zero deg) ----------------
__global__ __launch_bounds__(256) void k_h0(const float* __restrict__ x,
                                            const float* __restrict__ pos,
                                            const float* __restrict__ pw,
                                            const float* __restrict__ pb,
                                            float* __restrict__ h,
                                            int* __restrict__ deg) {
    int gid = blockIdx.x * 256 + threadIdx.x;
    if (gid < N_NODESC) deg[gid] = 0;
    int node = blockIdx.x * 2 + (threadIdx.x >> 7);
    int c = threadIdx.x & 127;
    float x0 = x[node * 3 + 0];
    float x1 = x[node * 3 + 1];
    float x2 = x[node * 3 + 2];
    float acc = x0 * pw[c] + x1 * pw[128 + c] + x2 * pw[256 + c];
    acc += pb[c];
    int dim = c >> 6;
    int inner = c & 63;
    int jj = inner & 31;
    float p = pos[node * 2 + dim];
    float omega = exp2f(-(float)jj * 0.41524101186092027f);
    float ang = p * omega;
    acc += (inner < 32) ? __sinf(ang) : __cosf(ang);
    h[(size_t)node * 128 + c] = acc;
}

// ---------------- degree histogram ----------------
__global__ __launch_bounds__(256) void k_deg(const int* __restrict__ edges, int* __restrict__ deg) {
    int e = blockIdx.x * 256 + threadIdx.x;
    if (e < N_EDGESC) {
        int2 e2 = ((const int2*)edges)[e];
        atomicAdd(&deg[e2.y], 1);
    }
}

// ---------------- exclusive scan (32768 = 1024 threads x 32) ----------------
__global__ __launch_bounds__(1024) void k_scan(const int* __restrict__ deg,
                                               int* __restrict__ off, int* __restrict__ cur,
                                               float* __restrict__ rs, float* __restrict__ bg) {
    __shared__ int ls[1024];
    int tid = threadIdx.x;
    int base = tid * 32;
    int v[32];
    int s = 0;
#pragma unroll
    for (int j = 0; j < 32; j++) { v[j] = deg[base + j]; s += v[j]; }
    ls[tid] = s;
    __syncthreads();
    for (int ofs = 1; ofs < 1024; ofs <<= 1) {
        int t = (tid >= ofs) ? ls[tid - ofs] : 0;
        __syncthreads();
        ls[tid] += t;
        __syncthreads();
    }
    int run = ls[tid] - s;
#pragma unroll
    for (int j = 0; j < 32; j++) {
        off[base + j] = run;
        cur[base + j] = run;
        int d = v[j];
        rs[base + j] = 1.f / (float)(d > 0 ? d : 1);
        bg[base + j] = d > 0 ? 1.f : 0.f;
        run += d;
    }
}

// ---------------- CSR fill (placement order nondeterministic; sorted in accum) ----------------
__global__ __launch_bounds__(256) void k_fill(const int* __restrict__ edges,
                                              int* __restrict__ cur, int* __restrict__ csr) {
    int e = blockIdx.x * 256 + threadIdx.x;
    if (e < N_EDGESC) {
        int2 e2 = ((const int2*)edges)[e];
        int pos = atomicAdd(&cur[e2.y], 1);
        csr[pos] = e2.x;
    }
}

// ---------------- dual-W GEMM: V = A@Wv ; U = A@Wu + bu  (double-buffered W) ----------------
__global__ __launch_bounds__(256, 2) void gemm_dualw(const float* __restrict__ A,
                                                     const float* __restrict__ Wv,
                                                     const float* __restrict__ Wu,
                                                     const float* __restrict__ bu,
                                                     float* __restrict__ V, float* __restrict__ U) {
    __shared__ float Wsv[2][16 * 128];
    __shared__ float Wsu[2][16 * 128];
    int tid = threadIdx.x;
    int cg = tid & 31;
    int rg = tid >> 5;
    int m0 = blockIdx.x * 32 + rg * 4;
    int c0 = cg * 4;
    const float* Ar = A + (size_t)m0 * 128;

    float accv[4][4], accu[4][4];
#pragma unroll
    for (int r = 0; r < 4; r++)
#pragma unroll
        for (int c = 0; c < 4; c++) { accv[r][c] = 0.f; accu[r][c] = 0.f; }

#define STAGE_DW(buf, kc)                                                          \
    {                                                                              \
        const float4* Wgv = (const float4*)(Wv + (size_t)(kc) * 128);              \
        const float4* Wgu = (const float4*)(Wu + (size_t)(kc) * 128);              \
        float4* Wlv = (float4*)Wsv[buf];                                           \
        float4* Wlu = (float4*)Wsu[buf];                                           \
        _Pragma("unroll") for (int i = 0; i < 2; i++) {                            \
            Wlv[tid + i * 256] = Wgv[tid + i * 256];                               \
            Wlu[tid + i * 256] = Wgu[tid + i * 256];                               \
        }                                                                          \
    }

    STAGE_DW(0, 0)
    __syncthreads();
    for (int c = 0; c < 8; c++) {
        int buf = c & 1;
        if (c + 1 < 8) STAGE_DW(buf ^ 1, (c + 1) * 16)
        int kc = c * 16;
#pragma unroll
        for (int k0 = 0; k0 < 16; k0 += 4) {
            float4 a[4];
#pragma unroll
            for (int r = 0; r < 4; r++) a[r] = *(const float4*)(Ar + r * 128 + kc + k0);
#pragma unroll
            for (int kk = 0; kk < 4; kk++) {
                float4 wv = *(const float4*)(Wsv[buf] + (k0 + kk) * 128 + c0);
                float4 wu = *(const float4*)(Wsu[buf] + (k0 + kk) * 128 + c0);
#pragma unroll
                for (int r = 0; r < 4; r++) {
                    float aa = ((const float*)&a[r])[kk];
                    accv[r][0] += aa * wv.x; accv[r][1] += aa * wv.y;
                    accv[r][2] += aa * wv.z; accv[r][3] += aa * wv.w;
                    accu[r][0] += aa * wu.x; accu[r][1] += aa * wu.y;
                    accu[r][2] += aa * wu.z; accu[r][3] += aa * wu.w;
                }
            }
        }
        __syncthreads();
    }
#undef STAGE_DW
#pragma unroll
    for (int r = 0; r < 4; r++) {
        int row = m0 + r;
        float4 ov, ou;
        ov.x = accv[r][0]; ov.y = accv[r][1]; ov.z = accv[r][2]; ov.w = accv[r][3];
        ou.x = accu[r][0] + bu[c0];
        ou.y = accu[r][1] + bu[c0 + 1];
        ou.z = accu[r][2] + bu[c0 + 2];
        ou.w = accu[r][3] + bu[c0 + 3];
        *(float4*)(V + (size_t)row * 128 + c0) = ov;
        *(float4*)(U + (size_t)row * 128 + c0) = ou;
    }
}

// ---------------- fused post-accum chain, FULL-W LDS staging (no in-loop barriers) ----------------
// stage1: aggT = (S@W2)*rs + b2*bg ; stage2: q = silu(h@U1a + aggT@U1b + ub1) ;
// stage3: h = h + qT@U2 + ub2 + p/r dots.
// Per pass: one 64KB W stage (2 barriers), then k=0..128 compute uninterrupted.
// FMA order per accumulator k-ascending (identical sequence to r17) -> bit-identical.
// LDS 80KB -> 2 blocks/CU; inter-block overlap covers stage windows.
__global__ __launch_bounds__(256, 2) void gemm_chain(const float* __restrict__ S,
                                                     float* __restrict__ h,
                                                     const float* __restrict__ W2,
                                                     const float* __restrict__ b2,
                                                     const float* __restrict__ rs,
                                                     const float* __restrict__ bg,
                                                     const float* __restrict__ U1a,
                                                     const float* __restrict__ U1b,
                                                     const float* __restrict__ ub1,
                                                     const float* __restrict__ U2,
                                                     const float* __restrict__ ub2,
                                                     const float* __restrict__ wrel,
                                                     const float* __restrict__ wroot,
                                                     float* __restrict__ pout,
                                                     float* __restrict__ rout) {
    __shared__ float Wf[128 * 128];   // 64KB: full weight matrix for current pass
    __shared__ float T[32 * 128];     // 16KB tile: agg, then q
    int tid = threadIdx.x;
    int cg = tid & 31;
    int rg = tid >> 5;
    int m0 = blockIdx.x * 32 + rg * 4;
    int c0 = cg * 4;
    const float* Sr = S + (size_t)m0 * 128;
    const float* hr = h + (size_t)m0 * 128;

    float acc1[4][4], acc2[4][4];

#define ZERO(acc)                                                          \
    {                                                                      \
        _Pragma("unroll") for (int r = 0; r < 4; r++)                      \
            _Pragma("unroll") for (int c = 0; c < 4; c++) acc[r][c] = 0.f; \
    }
// full 64KB stage: 4096 float4s over 256 threads = 16 each; 2 barriers total
#define STAGE_FULL(Wsrc)                                                   \
    {                                                                      \
        __syncthreads();                                                   \
        const float4* Wg = (const float4*)(Wsrc);                          \
        float4* Wl = (float4*)Wf;                                          \
        _Pragma("unroll") for (int i = 0; i < 16; i++)                     \
            Wl[tid + i * 256] = Wg[tid + i * 256];                         \
        __syncthreads();                                                   \
    }
// compute full k=0..128, A from global row base — no barriers inside
#define COMPUTE_GF(acc, Abase)                                             \
    for (int k0 = 0; k0 < 128; k0 += 4) {                                  \
        float4 a[4];                                                       \
        _Pragma("unroll") for (int r = 0; r < 4; r++)                      \
            a[r] = *(const float4*)((Abase) + r * 128 + k0);               \
        _Pragma("unroll") for (int kk = 0; kk < 4; kk++) {                 \
            float4 wv = *(const float4*)(Wf + (k0 + kk) * 128 + c0);       \
            _Pragma("unroll") for (int r = 0; r < 4; r++) {                \
                float aa = ((const float*)&a[r])[kk];                      \
                acc[r][0] += aa * wv.x; acc[r][1] += aa * wv.y;            \
                acc[r][2] += aa * wv.z; acc[r][3] += aa * wv.w;            \
            }                                                              \
        }                                                                  \
    }
// compute full k=0..128, A from LDS tile T — no barriers inside
#define COMPUTE_TF(acc)                                                    \
    for (int k0 = 0; k0 < 128; k0 += 4) {                                  \
        float4 a[4];                                                       \
        _Pragma("unroll") for (int r = 0; r < 4; r++)                      \
            a[r] = *(const float4*)(T + (rg * 4 + r) * 128 + k0);          \
        _Pragma("unroll") for (int kk = 0; kk < 4; kk++) {                 \
            float4 wv = *(const float4*)(Wf + (k0 + kk) * 128 + c0);       \
            _Pragma("unroll") for (int r = 0; r < 4; r++) {                \
                float aa = ((const float*)&a[r])[kk];                      \
                acc[r][0] += aa * wv.x; acc[r][1] += aa * wv.y;            \
                acc[r][2] += aa * wv.z; acc[r][3] += aa * wv.w;            \
            }                                                              \
        }                                                                  \
    }

    // ---- stage 1: acc1 = S@W2 ; aggT = acc1*rs + b2*bg ----
    ZERO(acc1)
    STAGE_FULL(W2)
    COMPUTE_GF(acc1, Sr)
#pragma unroll
    for (int r = 0; r < 4; r++) {
        int row = m0 + r;
        float rsv = rs[row];
        float bgv = bg[row];
        float4 o;
        float* op = (float*)&o;
#pragma unroll
        for (int c = 0; c < 4; c++) {
            float xv = acc1[r][c];
            xv *= rsv;
            xv += b2[c0 + c] * bgv;
            op[c] = xv;
        }
        *(float4*)(T + (rg * 4 + r) * 128 + c0) = o;
    }
    // (STAGE_FULL's leading barrier orders T-write vs readers)

    // ---- stage 2: acc1 = h@U1a ; acc2 = aggT@U1b ; q = silu(acc1+acc2+ub1) ----
    ZERO(acc1)
    STAGE_FULL(U1a)
    COMPUTE_GF(acc1, hr)
    ZERO(acc2)
    STAGE_FULL(U1b)
    COMPUTE_TF(acc2)
    __syncthreads();   // all reads of aggT done before overwrite
#pragma unroll
    for (int r = 0; r < 4; r++) {
        float4 o;
        float* op = (float*)&o;
#pragma unroll
        for (int c = 0; c < 4; c++) {
            float xv = acc1[r][c];
            xv += acc2[r][c];
            xv += ub1[c0 + c];
            op[c] = siluf(xv);
        }
        *(float4*)(T + (rg * 4 + r) * 128 + c0) = o;
    }

    // ---- stage 3: acc1 = qT@U2 ; h = acc1 + ub2 + h ; p/r dots ----
    ZERO(acc1)
    STAGE_FULL(U2)   // leading barrier makes qT visible to all waves
    COMPUTE_TF(acc1)
    float prel[4], prot[4];
#pragma unroll
    for (int r = 0; r < 4; r++) {
        int row = m0 + r;
        float4 o;
        float* op = (float*)&o;
#pragma unroll
        for (int c = 0; c < 4; c++) {
            float xv = acc1[r][c];
            xv *= 1.f;
            xv += ub2[c0 + c] * 1.f;
            xv += hr[r * 128 + c0 + c];
            op[c] = xv;
        }
        prel[r] = op[0] * wrel[c0] + op[1] * wrel[c0 + 1] + op[2] * wrel[c0 + 2] + op[3] * wrel[c0 + 3];
        prot[r] = op[0] * wroot[c0] + op[1] * wroot[c0 + 1] + op[2] * wroot[c0 + 2] + op[3] * wroot[c0 + 3];
        *(float4*)(h + (size_t)row * 128 + c0) = o;
    }
#pragma unroll
    for (int r = 0; r < 4; r++) {
        float a = prel[r], b = prot[r];
#pragma unroll
        for (int m = 1; m < 32; m <<= 1) {
            a += __shfl_xor(a, m);
            b += __shfl_xor(b, m);
        }
        if (cg == 0) { pout[m0 + r] = a; rout[m0 + r] = b; }
    }
#undef ZERO
#undef STAGE_FULL
#undef COMPUTE_GF
#undef COMPUTE_TF
}

// ---------------- fused sort + accum: wave per node (r16, kept) ----------------
__global__ __launch_bounds__(256) void k_accum_S(const float* __restrict__ v,
                                                 int* __restrict__ csr, const int* __restrict__ off,
                                                 const int* __restrict__ deg, float* S) {
    int d = blockIdx.x * 4 + (threadIdx.x >> 6);
    int lane = threadIdx.x & 63;
    int o = off[d], n = deg[d];
    float* srow = S + (size_t)d * 128;
    float2 u = *(const float2*)(srow + lane * 2);
    float2 a = {0.f, 0.f};

    // ---- sort segment ----
    int key0 = 0x7FFFFFFF, key1 = 0x7FFFFFFF;
    bool small = (n <= 128);
    if (small) {
        if (n > 1) {
            int i0 = 2 * lane, i1 = 2 * lane + 1;
            if (i0 < n) key0 = csr[o + i0];
            if (i1 < n) key1 = csr[o + i1];
            for (int k = 2; k <= 128; k <<= 1) {
                for (int j = k >> 1; j >= 2; j >>= 1) {
                    int p0 = __shfl_xor(key0, j >> 1);
                    int p1 = __shfl_xor(key1, j >> 1);
                    int vi0 = 2 * lane, vi1 = vi0 + 1;
                    bool keep0 = (((vi0 & j) == 0) == ((vi0 & k) == 0));
                    bool keep1 = (((vi1 & j) == 0) == ((vi1 & k) == 0));
                    key0 = keep0 ? min(key0, p0) : max(key0, p0);
                    key1 = keep1 ? min(key1, p1) : max(key1, p1);
                }
                {
                    bool asc = (((2 * lane) & k) == 0);
                    int lo = min(key0, key1), hi = max(key0, key1);
                    key0 = asc ? lo : hi;
                    key1 = asc ? hi : lo;
                }
            }
            if (2 * lane < n) csr[o + 2 * lane] = key0;
            if (2 * lane + 1 < n) csr[o + 2 * lane + 1] = key1;
        } else if (n == 1) {
            key0 = csr[o];
            key0 = __shfl(key0, 0);
        }
    } else {
        if (lane == 0) {
            for (int i = o + 1; i < o + n; i++) {
                int x = csr[i];
                int j = i - 1;
                while (j >= o && csr[j] > x) { csr[j + 1] = csr[j]; j--; }
                csr[j + 1] = x;
            }
        }
        __threadfence();
    }

    // ---- accumulate ----
    for (int base = 0; base < n; base += 64) {
        int cnt = min(64, n - base);
        int sall;
        if (small) {
            int src = (base + lane) >> 1;
            int e0 = __shfl(key0, src);
            int e1 = __shfl(key1, src);
            sall = (lane & 1) ? e1 : e0;
        } else {
            sall = (lane < cnt) ? csr[o + base + lane] : 0;
        }
        int j = 0;
        for (; j + 8 <= cnt; j += 8) {
            int s0 = __shfl(sall, j + 0), s1 = __shfl(sall, j + 1);
            int s2 = __shfl(sall, j + 2), s3 = __shfl(sall, j + 3);
            int s4 = __shfl(sall, j + 4), s5 = __shfl(sall, j + 5);
            int s6 = __shfl(sall, j + 6), s7 = __shfl(sall, j + 7);
            float2 w0 = *(const float2*)(v + (size_t)s0 * 128 + lane * 2);
            float2 w1 = *(const float2*)(v + (size_t)s1 * 128 + lane * 2);
            float2 w2 = *(const float2*)(v + (size_t)s2 * 128 + lane * 2);
            float2 w3 = *(const float2*)(v + (size_t)s3 * 128 + lane * 2);
            float2 w4 = *(const float2*)(v + (size_t)s4 * 128 + lane * 2);
            float2 w5 = *(const float2*)(v + (size_t)s5 * 128 + lane * 2);
            float2 w6 = *(const float2*)(v + (size_t)s6 * 128 + lane * 2);
            float2 w7 = *(const float2*)(v + (size_t)s7 * 128 + lane * 2);
            a.x += siluf(u.x + w0.x); a.y += siluf(u.y + w0.y);
            a.x += siluf(u.x + w1.x); a.y += siluf(u.y + w1.y);
            a.x += siluf(u.x + w2.x); a.y += siluf(u.y + w2.y);
            a.x += siluf(u.x + w3.x); a.y += siluf(u.y + w3.y);
            a.x += siluf(u.x + w4.x); a.y += siluf(u.y + w4.y);
            a.x += siluf(u.x + w5.x); a.y += siluf(u.y + w5.y);
            a.x += siluf(u.x + w6.x); a.y += siluf(u.y + w6.y);
            a.x += siluf(u.x + w7.x); a.y += siluf(u.y + w7.y);
        }
        for (; j < cnt; j++) {
            int s = __shfl(sall, j);
            float2 w = *(const float2*)(v + (size_t)s * 128 + lane * 2);
            a.x += siluf(u.x + w.x);
            a.y += siluf(u.y + w.y);
        }
    }
    *(float2*)(srow + lane * 2) = a;
}

// ---------------- score[d] = tanh( (sum p[src]) / cnt + rel_b + r[d] ) ----------------
__global__ __launch_bounds__(256) void k_score(const float* __restrict__ p, const float* __restrict__ r,
                                               const int* __restrict__ csr, const int* __restrict__ off,
                                               const int* __restrict__ deg, const float* __restrict__ relb,
                                               float* __restrict__ score) {
    int d = blockIdx.x * 4 + (threadIdx.x >> 6);
    int lane = threadIdx.x & 63;
    int o = off[d], n = deg[d];
    float a = 0.f;
    for (int j = lane; j < n; j += 64) a += p[csr[o + j]];
    for (int m = 32; m > 0; m >>= 1) a += __shfl_xor(a, m);
    if (lane == 0) {
        float cnt = (float)(n > 0 ? n : 1);
        score[d] = tanhf(a / cnt + relb[0] + r[d]);
    }
}

// ---------------- per-graph exact top-k via radix-select + direct ranking ----------------
__global__ __launch_bounds__(1024) void k_topk(const float* __restrict__ score, const float* __restrict__ h,
                                               float* __restrict__ out) {
    __shared__ u32 ms[NPG];
    __shared__ u32 hist[256];
    __shared__ u32 sbuf[1024];
    __shared__ u64 sel[KOUT];
    __shared__ float ordv[KOUT];
    __shared__ int ordi[KOUT];
    __shared__ u32 selCnt, sPrefix, sNeed, sB;

    int g = blockIdx.x;
    int tid = threadIdx.x;

    for (int i = tid; i < NPG; i += 1024) {
        u32 u = __float_as_uint(score[(size_t)g * NPG + i]);
        ms[i] = (u & 0x80000000u) ? ~u : (u | 0x80000000u);
    }
    if (tid == 0) { sNeed = KOUT; sPrefix = 0; selCnt = 0; }
    __syncthreads();

    for (int pass = 0; pass < 4; pass++) {
        int shift = 24 - pass * 8;
        if (tid < 256) hist[tid] = 0;
        __syncthreads();
        u32 pfx = sPrefix;
        for (int i = tid; i < NPG; i += 1024) {
            u32 v = ms[i];
            if (pass == 0 || (v >> (shift + 8)) == pfx)
                atomicAdd(&hist[(v >> shift) & 255u], 1u);
        }
        __syncthreads();
        if (tid < 256) sbuf[tid] = hist[tid];
        __syncthreads();
        for (int ofs = 1; ofs < 256; ofs <<= 1) {
            u32 t = 0;
            if (tid < 256 && tid + ofs < 256) t = sbuf[tid + ofs];
            __syncthreads();
            if (tid < 256) sbuf[tid] += t;
            __syncthreads();
        }
        u32 need = sNeed;
        if (tid < 256) {
            if (sbuf[tid] >= need && (tid == 255 || sbuf[tid + 1] < need)) sB = (u32)tid;
        }
        __syncthreads();
        if (tid == 0) {
            u32 B = sB;
            u32 above = (B == 255) ? 0u : sbuf[B + 1];
            sNeed = need - above;
            sPrefix = (sPrefix << 8) | B;
        }
        __syncthreads();
    }
    u32 T = sPrefix;
    u32 rTie = sNeed;

    int base = tid * 8;
    u32 lc = 0;
#pragma unroll
    for (int j = 0; j < 8; j++) lc += (ms[base + j] == T);
    __syncthreads();
    sbuf[tid] = lc;
    __syncthreads();
    u32 own = lc;
    for (int ofs = 1; ofs < 1024; ofs <<= 1) {
        u32 t = (tid >= ofs) ? sbuf[tid - ofs] : 0;
        __syncthreads();
        sbuf[tid] += t;
        __syncthreads();
    }
    u32 excl = sbuf[tid] - own;

#pragma unroll
    for (int j = 0; j < 8; j++) {
        int i = base + j;
        u32 v = ms[i];
        bool pick = (v > T) || ((v == T) && (excl < rTie));
        if (v == T) excl++;
        if (pick) {
            u32 slot = atomicAdd(&selCnt, 1u);
            sel[slot] = ((u64)v << 32) | (u32)(NPG - 1 - i);
        }
    }
    __syncthreads();

    if (tid < KOUT) {
        u64 mine = sel[tid];
        int rank = 0;
        for (int j = 0; j < KOUT; j++) rank += (sel[j] > mine);
        u32 v = (u32)(mine >> 32);
        int idx = NPG - 1 - (int)(mine & 0xFFFFFFFFu);
        u32 uu = (v & 0x80000000u) ? (v & 0x7FFFFFFFu) : ~v;
        ordv[rank] = __uint_as_float(uu);
        ordi[rank] = idx;
    }
    __syncthreads();

    for (int t = tid; t < KOUT * 128; t += 1024) {
        int r = t >> 7, c = t & 127;
        int node = g * NPG + ordi[r];
        out[((size_t)g * KOUT + r) * 128 + c] = h[(size_t)node * 128 + c] * ordv[r];
    }
    for (int t = tid; t < KOUT; t += 1024)
        out[(size_t)4 * KOUT * 128 + (size_t)g * KOUT + t] = (float)g;
}

extern "C" void kernel_launch(void* const* d_in, const int* in_sizes, int n_in,
                              void* d_out, int out_size, void* d_ws, size_t ws_size,
                              hipStream_t stream) {
    const float* x        = (const float*)d_in[0];
    const float* mesh_pos = (const float*)d_in[1];
    const int*   edges    = (const int*)d_in[2];
    const float* proj_w   = (const float*)d_in[4];
    const float* proj_b   = (const float*)d_in[5];
    const float* msg_w1   = (const float*)d_in[6];
    const float* msg_b1   = (const float*)d_in[7];
    const float* msg_w2   = (const float*)d_in[8];
    const float* msg_b2   = (const float*)d_in[9];
    const float* upd_w1   = (const float*)d_in[10];
    const float* upd_b1   = (const float*)d_in[11];
    const float* upd_w2   = (const float*)d_in[12];
    const float* upd_b2   = (const float*)d_in[13];
    const float* pool_rel_w  = (const float*)d_in[14];
    const float* pool_rel_b  = (const float*)d_in[15];
    const float* pool_root_w = (const float*)d_in[16];
    float* out = (float*)d_out;

    // workspace: 3 x 16MB node buffers + small arrays (~51.1MB)
    char* w = (char*)d_ws;
    float* h  = (float*)(w);                   // h0 -> h_new (in place)
    float* v  = (float*)(w + (1ull << 24));    // v (dead after accum)
    float* S  = (float*)(w + (2ull << 24));    // u -> S
    char* sm  = w + (3ull << 24);
    int*   deg   = (int*)(sm);
    int*   off   = (int*)(sm + 131072);
    int*   cur   = (int*)(sm + 262144);
    float* rsA   = (float*)(sm + 393216);
    float* bgA   = (float*)(sm + 524288);
    float* pp    = (float*)(sm + 655360);
    float* rr    = (float*)(sm + 786432);
    float* score = (float*)(sm + 917504);
    int*   csr   = (int*)(sm + 1048576);       // 2MB

    k_h0<<<N_NODESC / 2, 256, 0, stream>>>(x, mesh_pos, proj_w, proj_b, h, deg);
    k_deg<<<N_EDGESC / 256, 256, 0, stream>>>(edges, deg);
    k_scan<<<1, 1024, 0, stream>>>(deg, off, cur, rsA, bgA);
    k_fill<<<N_EDGESC / 256, 256, 0, stream>>>(edges, cur, csr);

    // v = h@W1b ; S = h@W1a + b1   (one pass over h)
    gemm_dualw<<<1024, 256, 0, stream>>>(h, msg_w1 + 128 * 128, msg_w1, msg_b1, v, S);
    // sort csr segments + S[d] = sum_e silu( S[d] + v[src_e] )   (in place)
    k_accum_S<<<N_NODESC / 4, 256, 0, stream>>>(v, csr, off, deg, S);
    // fused: agg = (S@W2)*rs + b2*bg ; q = silu(h@U1a + agg@U1b + ub1) ;
    //        h = h + q@U2 + ub2 ; p/r dots
    gemm_chain<<<1024, 256, 0, stream>>>(S, h, msg_w2, msg_b2, rsA, bgA,
                                         upd_w1, upd_w1 + 128 * 128, upd_b1,
                                         upd_w2, upd_b2,
                                         pool_rel_w, pool_root_w, pp, rr);

    k_score<<<N_NODESC / 4, 256, 0, stream>>>(pp, rr, csr, off, deg, pool_rel_b, score);
    k_topk<<<4, 1024, 0, stream>>>(score, h, out);
}